// Round 8
// baseline (240.321 us; speedup 1.0000x reference)
//
#include <hip/hip_runtime.h>

#define B_   64
#define T_   2048
#define TM1  2047
#define D_   64

#define PID(i,j) ((i)*((i)-1)/2 + (j))

typedef __attribute__((ext_vector_type(8))) short bf16x8;
typedef __attribute__((ext_vector_type(4))) float f32x4;

__device__ __forceinline__ unsigned f2bf(float v) {
    unsigned u = __float_as_uint(v);
    u = (u + 0x7FFFu + ((u >> 16) & 1u)) >> 16;   // RNE
    return u;
}
__device__ __forceinline__ float bf2f(unsigned s) {
    return __uint_as_float(s << 16);
}

// ---------------- K0: pack proj_w into per-lane B-fragment layout (bf16, 32KB) [proven R6/R7]
__global__ void k_prep(const float* __restrict__ pw, unsigned short* __restrict__ pwB)
{
    int idx = blockIdx.x * 256 + threadIdx.x;     // 16384 total
    int j  = idx & 7;
    int l  = (idx >> 3) & 63;
    int ks = (idx >> 9) & 7;
    int nt = idx >> 12;
    int k  = ks * 32 + ((l >> 4) << 3) + j;
    int o  = nt * 16 + (l & 15);
    pwB[idx] = (unsigned short)f2bf(pw[k * 64 + o]);
}

// ---------------- K1: 2-lane-split expm. Lane pair (tl) owns one (t, g) matrix;
// lane h owns columns 4h..4h+3. Block: 256 thr = 4 waves = 4 groups x 32 t.
__global__ __launch_bounds__(256) void k_expm_s2(
    const float* __restrict__ x, const float* __restrict__ mask,
    const float* __restrict__ Wd, const float* __restrict__ lng,
    const float* __restrict__ lnb, const unsigned short* __restrict__ pwB,
    const float* __restrict__ pb, unsigned short* __restrict__ fbf,
    float* __restrict__ pooled, float* __restrict__ denom)
{
    __shared__ __align__(16) unsigned char smem[20480];
    float* xT = (float*)smem;                       // [33][65] f32 (8.6KB), then f-stage 16KB

    const int tid  = threadIdx.x;
    const int lane = tid & 63;
    const int g    = __builtin_amdgcn_readfirstlane(tid >> 6);
    const int tl   = lane >> 1;
    const int h    = lane & 1;
    const int bl   = blockIdx.x >> 6;
    const int t0   = (blockIdx.x & 63) << 5;

    // stage x rows t0..t0+32 (33 rows x 64 ch), padded stride 65
    const float* xb = x + (size_t)bl * (T_ * D_);
    for (int idx = tid; idx < 33 * 64; idx += 256) {
        int r = idx >> 6, c = idx & 63;
        int tr = t0 + r;
        xT[r * 65 + c] = (tr < T_) ? xb[tr * 64 + c] : 0.f;
    }
    __syncthreads();

    const float* mrow = mask + bl * T_;

    // fused masked x-pool + denom (rows t0..t0+31 all exist in x)
    {
        int c = tid & 63, rg = tid >> 6;
        float ps = 0.f;
        #pragma unroll
        for (int i = 0; i < 8; ++i) {
            int r = rg * 8 + i;
            ps = fmaf(xT[r * 65 + c], mrow[t0 + r], ps);
        }
        atomicAdd(&pooled[bl * 64 + c], ps);
        if (g == 0) {
            float dv = (lane < 32) ? mrow[t0 + lane] : 0.f;
            #pragma unroll
            for (int off = 32; off >= 1; off >>= 1) dv += __shfl_xor(dv, off);
            if (lane == 0) atomicAdd(&denom[bl], dv);
        }
    }

    const int t = t0 + tl;
    const bool valid = (t < TM1);
    const float mk = valid ? mrow[t + 1] : 0.f;

    // Mlie: lane handles 8 of the 16 channels; combine halves via shfl_xor(1)
    float al[28];
    #pragma unroll
    for (int p = 0; p < 28; ++p) al[p] = 0.f;
    const float* Wg = Wd + g * (16 * 64) + h * (8 * 64);
    #pragma unroll
    for (int d = 0; d < 8; ++d) {
        int c = g * 16 + h * 8 + d;
        float dxd = (xT[(tl + 1) * 65 + c] - xT[tl * 65 + c]) * mk;
        const float* Wrow = Wg + d * 64;
        #pragma unroll
        for (int i = 1; i < 8; ++i)
            #pragma unroll
            for (int j = 0; j < i; ++j)
                al[PID(i, j)] = fmaf(dxd, Wrow[i * 8 + j], al[PID(i, j)]);
    }
    #pragma unroll
    for (int p = 0; p < 28; ++p) al[p] = (al[p] + __shfl_xor(al[p], 1)) * 0.0625f;
    __syncthreads();                                // xT dead; smem becomes f-stage

    // Taylor-6 Horner on own 4 columns (column update is column-local)
    float Rc[4][8];                                 // Rc[jj][i] = R[i][4h+jj]
    #pragma unroll
    for (int jj = 0; jj < 4; ++jj)
        #pragma unroll
        for (int i = 0; i < 8; ++i)
            Rc[jj][i] = (i == 4 * h + jj) ? 1.f : 0.f;
    for (int k = 6; k >= 1; --k) {
        float invk = 1.f / (float)k;
        #pragma unroll
        for (int jj = 0; jj < 4; ++jj) {
            int j = 4 * h + jj;
            float tmp[8];
            #pragma unroll
            for (int i = 0; i < 8; ++i) tmp[i] = Rc[jj][i];
            #pragma unroll
            for (int i = 0; i < 8; ++i) {
                float s = 0.f;
                #pragma unroll
                for (int kk = 0; kk < 8; ++kk) {
                    if (kk == i) continue;
                    float a = (i > kk) ? al[PID(i, kk)] : -al[PID(kk, i)];
                    s = fmaf(a, tmp[kk], s);
                }
                Rc[jj][i] = ((i == j) ? 1.f : 0.f) + invk * s;
            }
        }
    }

    // 4 squarings; partner's columns streamed via shfl_xor(1)
    for (int sq = 0; sq < 4; ++sq) {
        float acc2[4][8];
        #pragma unroll
        for (int jj = 0; jj < 4; ++jj)
            #pragma unroll
            for (int i = 0; i < 8; ++i) acc2[jj][i] = 0.f;
        #pragma unroll
        for (int kk = 0; kk < 8; ++kk) {
            const int oj = kk & 3;
            float colbuf[8];
            #pragma unroll
            for (int i = 0; i < 8; ++i) {
                float other = __shfl_xor(Rc[oj][i], 1);
                colbuf[i] = ((kk >> 2) == h) ? Rc[oj][i] : other;
            }
            #pragma unroll
            for (int jj = 0; jj < 4; ++jj) {
                float sc = Rc[jj][kk];
                #pragma unroll
                for (int i = 0; i < 8; ++i)
                    acc2[jj][i] = fmaf(colbuf[i], sc, acc2[jj][i]);
            }
        }
        #pragma unroll
        for (int jj = 0; jj < 4; ++jj)
            #pragma unroll
            for (int i = 0; i < 8; ++i) Rc[jj][i] = acc2[jj][i];
    }

    // LayerNorm over 64 (2-lane reduce)
    float sum = 0.f, ssq = 0.f;
    #pragma unroll
    for (int jj = 0; jj < 4; ++jj)
        #pragma unroll
        for (int i = 0; i < 8; ++i) { float v = Rc[jj][i]; sum += v; ssq = fmaf(v, v, ssq); }
    sum += __shfl_xor(sum, 1);
    ssq += __shfl_xor(ssq, 1);
    float mu   = sum * (1.f / 64.f);
    float var  = ssq * (1.f / 64.f) - mu * mu;
    float rstd = rsqrtf(var + 1e-5f);

    // stage LN'd f bf16: row tl (512B = 32 x 16B granules), granule (g*8+i)^(tl&7), half h
    #pragma unroll
    for (int i = 0; i < 8; ++i) {
        int e0 = i * 8 + 4 * h;
        float v0 = fmaf((Rc[0][i] - mu) * rstd, lng[e0],     lnb[e0]);
        float v1 = fmaf((Rc[1][i] - mu) * rstd, lng[e0 + 1], lnb[e0 + 1]);
        float v2 = fmaf((Rc[2][i] - mu) * rstd, lng[e0 + 2], lnb[e0 + 2]);
        float v3 = fmaf((Rc[3][i] - mu) * rstd, lng[e0 + 3], lnb[e0 + 3]);
        uint2 pk = make_uint2(f2bf(v0) | (f2bf(v1) << 16), f2bf(v2) | (f2bf(v3) << 16));
        int g16 = (g * 8 + i) ^ (tl & 7);
        *(uint2*)(smem + tl * 512 + g16 * 16 + h * 8) = pk;
    }
    __syncthreads();

    // MFMA proj: M=32, N=64, K=256. wave = (rt = g&1 row-tile, nh = g>>1 col-half)
    const int rt = g & 1;
    const int nh = g >> 1;
    f32x4 acc[2];
    acc[0] = (f32x4)(0.f); acc[1] = (f32x4)(0.f);
    const int arow = rt * 16 + (lane & 15);
    #pragma unroll
    for (int ks = 0; ks < 8; ++ks) {
        int c16 = ks * 4 + (lane >> 4);
        bf16x8 a = *(const bf16x8*)(smem + arow * 512 + (c16 ^ (arow & 7)) * 16);
        #pragma unroll
        for (int ntl = 0; ntl < 2; ++ntl) {
            int ntg = nh * 2 + ntl;
            bf16x8 bb = *(const bf16x8*)(pwB + (((ntg * 8 + ks) * 64 + lane) << 3));
            acc[ntl] = __builtin_amdgcn_mfma_f32_16x16x32_bf16(a, bb, acc[ntl], 0, 0, 0);
        }
    }

    // epilogue: bias, pooled_f (interp-adjoint), restage f
    unsigned short* fosh = (unsigned short*)(smem + 16384);  // [32][64] bf16
    float bias0 = pb[(nh * 2) * 16 + (lane & 15)];
    float bias1 = pb[(nh * 2 + 1) * 16 + (lane & 15)];
    float pf0 = 0.f, pf1 = 0.f;
    #pragma unroll
    for (int r = 0; r < 4; ++r) {
        int pl = rt * 16 + ((lane >> 4) << 2) + r;
        int p  = t0 + pl;
        float gam = 0.f;
        if (p < TM1) {
            float mp  = mrow[p];
            float mp1 = mrow[p + 1];
            float wlo = (p + 1.5f) * (1.f / 2048.f);
            float whi = 1.f - (p + 0.5f) * (1.f / 2048.f);
            if (p == 0)          gam = mp + mp1 * wlo;
            else if (p == 2046)  gam = mp * whi + mp1;
            else                 gam = mp * whi + mp1 * wlo;
        }
        float fv0 = acc[0][r] + bias0;
        float fv1 = acc[1][r] + bias1;
        pf0 = fmaf(gam, fv0, pf0);
        pf1 = fmaf(gam, fv1, pf1);
        fosh[pl * 64 + (nh * 2) * 16 + (lane & 15)]     = (unsigned short)f2bf(fv0);
        fosh[pl * 64 + (nh * 2 + 1) * 16 + (lane & 15)] = (unsigned short)f2bf(fv1);
    }
    pf0 += __shfl_xor(pf0, 16); pf0 += __shfl_xor(pf0, 32);
    pf1 += __shfl_xor(pf1, 16); pf1 += __shfl_xor(pf1, 32);
    if (lane < 16) {
        atomicAdd(&pooled[bl * 64 + (nh * 2) * 16 + lane], pf0);
        atomicAdd(&pooled[bl * 64 + (nh * 2 + 1) * 16 + lane], pf1);
    }
    __syncthreads();

    // coalesced bf16 output: 32 rows x 128B
    {
        int row = tid >> 3, c8 = tid & 7;
        int p = t0 + row;
        if (p < TM1) {
            uint4 vv = *(const uint4*)(fosh + row * 64 + c8 * 8);
            *(uint4*)(fbf + ((size_t)bl * TM1 + p) * 64 + c8 * 8) = vv;
        }
    }
}

// ---------------- K2: SE gate (recomputed per block) + apply. 16 t per block.
__global__ void k_apply2(const float* __restrict__ x, const unsigned short* __restrict__ fbf,
                         const float* __restrict__ pooled, const float* __restrict__ denom,
                         const float* __restrict__ w1, const float* __restrict__ b1,
                         const float* __restrict__ w2, const float* __restrict__ b2,
                         float* __restrict__ out)
{
    __shared__ float pl_[64];
    __shared__ float hid[4];
    __shared__ __align__(16) float sgate[64];
    const int b = blockIdx.x >> 7;
    const int o = threadIdx.x;
    if (o < 64) pl_[o] = pooled[b * 64 + o] / denom[b];
    __syncthreads();
    if (o < 4) {
        float hv = b1[o];
        for (int e = 0; e < 64; ++e) hv = fmaf(pl_[e], w1[e * 4 + o], hv);
        hid[o] = 0.5f * hv * (1.f + erff(hv * 0.70710678118654752f));
    }
    __syncthreads();
    if (o < 64) {
        float sv = b2[o];
        #pragma unroll
        for (int hh = 0; hh < 4; ++hh) sv = fmaf(hid[hh], w2[hh * 64 + o], sv);
        sgate[o] = 1.f / (1.f + expf(-sv));
    }
    __syncthreads();

    const int o4   = (threadIdx.x & 15) << 2;
    const int tloc = threadIdx.x >> 4;
    const int t    = ((blockIdx.x & 127) << 4) + tloc;
    float pos = fminf(fmaxf((t + 0.5f) * (2047.f / 2048.f) - 0.5f, 0.f), 2046.f);
    int   i0  = (int)pos;
    float w   = pos - (float)i0;
    int   i1  = min(i0 + 1, 2046);
    const unsigned short* fb = fbf + (size_t)b * (TM1 * 64);
    uint2 u0 = *(const uint2*)(fb + i0 * 64 + o4);
    uint2 u1 = *(const uint2*)(fb + i1 * 64 + o4);
    size_t base = ((size_t)b * T_ + t) * 64 + o4;
    float4 xv = *(const float4*)(x + base);
    float4 sv = *(const float4*)(&sgate[o4]);
    float4 ov;
    float f00 = bf2f(u0.x & 0xffffu), f01 = bf2f(u0.x >> 16);
    float f02 = bf2f(u0.y & 0xffffu), f03 = bf2f(u0.y >> 16);
    float f10 = bf2f(u1.x & 0xffffu), f11 = bf2f(u1.x >> 16);
    float f12 = bf2f(u1.y & 0xffffu), f13 = bf2f(u1.y >> 16);
    ov.x = fmaf(xv.x + f00 * (1.f - w) + f10 * w, sv.x, xv.x);
    ov.y = fmaf(xv.y + f01 * (1.f - w) + f11 * w, sv.y, xv.y);
    ov.z = fmaf(xv.z + f02 * (1.f - w) + f12 * w, sv.z, xv.z);
    ov.w = fmaf(xv.w + f03 * (1.f - w) + f13 * w, sv.w, xv.w);
    *(float4*)(out + base) = ov;
}

extern "C" void kernel_launch(void* const* d_in, const int* in_sizes, int n_in,
                              void* d_out, int out_size, void* d_ws, size_t ws_size,
                              hipStream_t stream)
{
    const float* x    = (const float*)d_in[0];
    const float* mask = (const float*)d_in[1];
    const float* Wd   = (const float*)d_in[2];
    const float* lng  = (const float*)d_in[3];
    const float* lnb  = (const float*)d_in[4];
    const float* pw   = (const float*)d_in[5];
    const float* pb   = (const float*)d_in[6];
    const float* sw1  = (const float*)d_in[7];
    const float* sb1  = (const float*)d_in[8];
    const float* sw2  = (const float*)d_in[9];
    const float* sb2  = (const float*)d_in[10];

    float* out    = (float*)d_out;
    float* pooled = (float*)d_ws;                        // 4096
    float* denom  = pooled + 4096;                       // 64
    unsigned short* pwB = (unsigned short*)(denom + 64); // 16384 shorts (32KB)
    unsigned short* fbf = pwB + 16384;                   // B*TM1*64 shorts (16.8MB)

    hipMemsetAsync(pooled, 0, (4096 + 64) * sizeof(float), stream);

    hipLaunchKernelGGL(k_prep, dim3(64), dim3(256), 0, stream, pw, pwB);
    hipLaunchKernelGGL(k_expm_s2, dim3(4096), dim3(256), 0, stream,
                       x, mask, Wd, lng, lnb, pwB, pb, fbf, pooled, denom);
    hipLaunchKernelGGL(k_apply2, dim3(8192), dim3(256), 0, stream,
                       x, fbf, pooled, denom, sw1, sb1, sw2, sb2, out);

    hipMemcpyAsync(out + (size_t)B_ * T_ * D_, mask,
                   (size_t)B_ * T_ * sizeof(float), hipMemcpyDeviceToDevice, stream);
}

// Round 9
// 197.475 us; speedup vs baseline: 1.2170x; 1.2170x over previous
//
#include <hip/hip_runtime.h>

#define B_   64
#define T_   2048
#define TM1  2047
#define D_   64

#define PID(i,j) ((i)*((i)-1)/2 + (j))
#define UID(i,j) ((i)*8 + (j) - (i)*((i)+1)/2)   // upper-tri incl diag, i<=j

typedef __attribute__((ext_vector_type(8))) short bf16x8;
typedef __attribute__((ext_vector_type(4))) float f32x4;

__device__ __forceinline__ unsigned f2bf(float v) {
    unsigned u = __float_as_uint(v);
    u = (u + 0x7FFFu + ((u >> 16) & 1u)) >> 16;   // RNE
    return u;
}
__device__ __forceinline__ float bf2f(unsigned s) {
    return __uint_as_float(s << 16);
}

// ---------------- K0: pack proj_w B-fragments (bf16, 32KB) + zero pooled/denom
__global__ void k_prep(const float* __restrict__ pw, unsigned short* __restrict__ pwB,
                       float* __restrict__ pooled)
{
    int idx = blockIdx.x * 256 + threadIdx.x;     // 16384 total
    int j  = idx & 7;
    int l  = (idx >> 3) & 63;
    int ks = (idx >> 9) & 7;
    int nt = idx >> 12;
    int k  = ks * 32 + ((l >> 4) << 3) + j;
    int o  = nt * 16 + (l & 15);
    pwB[idx] = (unsigned short)f2bf(pw[k * 64 + o]);
    if (idx < 4160) pooled[idx] = 0.f;            // pooled[4096] + denom[64]
}

// ---------------- K1: x-pool + dX -> Mlie -> expm(s=3, even/odd deg-7) -> LN
//                     -> MFMA proj -> f bf16 + pooled_f ; denom
// (256,3): AGPR-overflow regime proven spill-safe-ish (R2/R7); (256,4) hard-spills (R3).
__global__ __launch_bounds__(256, 3) void k_expm_f3(
    const float* __restrict__ x, const float* __restrict__ mask,
    const float* __restrict__ Wd, const float* __restrict__ lng,
    const float* __restrict__ lnb, const unsigned short* __restrict__ pwB,
    const float* __restrict__ pb, unsigned short* __restrict__ fbf,
    float* __restrict__ pooled, float* __restrict__ denom)
{
    __shared__ __align__(16) unsigned char smem[32768];
    float* xT = (float*)smem;                       // phase 1: 64x65 f32 (16.6KB)

    const int tid  = threadIdx.x;
    const int lane = tid & 63;
    const int wq   = __builtin_amdgcn_readfirstlane(tid >> 6);
    const int bl   = blockIdx.x >> 5;
    const int t0   = (blockIdx.x & 31) << 6;

    const float* xb = x + (size_t)bl * (T_ * D_);
    for (int idx = tid; idx < 65 * 64; idx += 256) {
        int r = idx >> 6, c = idx & 63;
        int tr = t0 + r;
        xT[c * 65 + r] = (tr < T_) ? xb[tr * 64 + c] : 0.f;
    }
    __syncthreads();

    const int t = t0 + lane;
    const bool valid = (t < TM1);
    const float* mrow = mask + bl * T_;
    const float mk = valid ? mrow[t + 1] : 0.f;

    // fused masked x-pooling (xT live; rows t0..t0+63 belong to this block)
    {
        const int c  = tid & 63;
        const int rg = tid >> 6;
        float psum = 0.f;
        #pragma unroll
        for (int i = 0; i < 16; ++i) {
            int r = rg * 16 + i;
            psum = fmaf(xT[c * 65 + r], mrow[t0 + r], psum);
        }
        atomicAdd(&pooled[bl * 64 + c], psum);
        if (wq == 0) {
            float dv = mrow[t0 + lane];
            #pragma unroll
            for (int off = 32; off >= 1; off >>= 1) dv += __shfl_xor(dv, off);
            if (lane == 0) atomicAdd(&denom[bl], dv);
        }
    }

    float al[28];
    #pragma unroll
    for (int p = 0; p < 28; ++p) al[p] = 0.f;
    const float* Wg = Wd + wq * (16 * 64);
    #pragma unroll
    for (int d = 0; d < 16; ++d) {
        const float* col = &xT[(wq * 16 + d) * 65 + lane];
        float dxd = (col[1] - col[0]) * mk;
        const float* Wrow = Wg + d * 64;
        #pragma unroll
        for (int i = 1; i < 8; ++i)
            #pragma unroll
            for (int j = 0; j < i; ++j)
                al[PID(i, j)] = fmaf(dxd, Wrow[i * 8 + j], al[PID(i, j)]);
    }
    __syncthreads();                                // xT dead; smem reused for f staging

    #pragma unroll
    for (int p = 0; p < 28; ++p) al[p] *= 0.125f;   // s=3 scaling

    // ---- even/odd expm: B = A^2 (sym, ut36), B2 = B^2, B3 = B*B2
    float Bu[36];
    #pragma unroll
    for (int i = 0; i < 8; ++i)
        #pragma unroll
        for (int j = i; j < 8; ++j) {
            float s = 0.f;
            #pragma unroll
            for (int k = 0; k < 8; ++k) {
                if (k == i || k == j) continue;
                float aki = (k > i) ? al[PID(k, i)] : -al[PID(i, k)];
                float akj = (k > j) ? al[PID(k, j)] : -al[PID(j, k)];
                s = fmaf(aki, akj, s);
            }
            Bu[UID(i, j)] = -s;
        }
    float B2u[36];
    #pragma unroll
    for (int i = 0; i < 8; ++i)
        #pragma unroll
        for (int j = i; j < 8; ++j) {
            float s = 0.f;
            #pragma unroll
            for (int k = 0; k < 8; ++k) {
                int l1 = (i < k) ? i : k, h1 = (i < k) ? k : i;
                int l2 = (k < j) ? k : j, h2 = (k < j) ? j : k;
                s = fmaf(Bu[UID(l1, h1)], Bu[UID(l2, h2)], s);
            }
            B2u[UID(i, j)] = s;
        }
    float B3u[36];
    #pragma unroll
    for (int i = 0; i < 8; ++i)
        #pragma unroll
        for (int j = i; j < 8; ++j) {
            float s = 0.f;
            #pragma unroll
            for (int k = 0; k < 8; ++k) {
                int l1 = (i < k) ? i : k, h1 = (i < k) ? k : i;
                int l2 = (k < j) ? k : j, h2 = (k < j) ? j : k;
                s = fmaf(Bu[UID(l1, h1)], B2u[UID(l2, h2)], s);
            }
            B3u[UID(i, j)] = s;
        }
    // in-place: Bu <- c0 = I + B/2 + B2/24 + B3/720 ; B2u <- c1 = I + B/6 + B2/120 + B3/5040
    #pragma unroll
    for (int i = 0; i < 8; ++i)
        #pragma unroll
        for (int j = i; j < 8; ++j) {
            int id = UID(i, j);
            float b = Bu[id], b2 = B2u[id], b3 = B3u[id];
            float idm = (i == j) ? 1.f : 0.f;
            Bu[id]  = fmaf(b3, 1.f/720.f,  fmaf(b2, 1.f/24.f,  fmaf(b, 0.5f,     idm)));
            B2u[id] = fmaf(b3, 1.f/5040.f, fmaf(b2, 1.f/120.f, fmaf(b, 1.f/6.f,  idm)));
        }
    // R = c0 + A*c1
    float R[64];
    #pragma unroll
    for (int i = 0; i < 8; ++i)
        #pragma unroll
        for (int j = 0; j < 8; ++j) {
            int lo = (i < j) ? i : j, hi = (i < j) ? j : i;
            float s = Bu[UID(lo, hi)];
            #pragma unroll
            for (int k = 0; k < 8; ++k) {
                if (k == i) continue;
                float aik = (i > k) ? al[PID(i, k)] : -al[PID(k, i)];
                int l2 = (k < j) ? k : j, h2 = (k < j) ? j : k;
                s = fmaf(aik, B2u[UID(l2, h2)], s);
            }
            R[i * 8 + j] = s;
        }
    // 3 squarings
    for (int sq = 0; sq < 3; ++sq) {
        float nw[64];
        #pragma unroll
        for (int i = 0; i < 8; ++i)
            #pragma unroll
            for (int j = 0; j < 8; ++j) {
                float s = 0.f;
                #pragma unroll
                for (int kk = 0; kk < 8; ++kk)
                    s = fmaf(R[i * 8 + kk], R[kk * 8 + j], s);
                nw[i * 8 + j] = s;
            }
        #pragma unroll
        for (int e = 0; e < 64; ++e) R[e] = nw[e];
    }

    float sum = 0.f, ssq = 0.f;
    #pragma unroll
    for (int e = 0; e < 64; ++e) { sum += R[e]; ssq = fmaf(R[e], R[e], ssq); }
    float mu   = sum * (1.f / 64.f);
    float var  = ssq * (1.f / 64.f) - mu * mu;
    float rstd = rsqrtf(var + 1e-5f);

    // stage LN'd f as bf16 into LDS: row=lane (512B), 8B slots XOR-swizzled
    #pragma unroll
    for (int eq = 0; eq < 16; ++eq) {
        int e = eq * 4;
        float v0 = fmaf((R[e]   - mu) * rstd, lng[e],   lnb[e]);
        float v1 = fmaf((R[e+1] - mu) * rstd, lng[e+1], lnb[e+1]);
        float v2 = fmaf((R[e+2] - mu) * rstd, lng[e+2], lnb[e+2]);
        float v3 = fmaf((R[e+3] - mu) * rstd, lng[e+3], lnb[e+3]);
        uint2 pk = make_uint2(f2bf(v0) | (f2bf(v1) << 16), f2bf(v2) | (f2bf(v3) << 16));
        int slot = wq * 16 + eq;
        int sw = slot ^ ((lane & 7) << 1);
        *(uint2*)(smem + lane * 512 + sw * 8) = pk;
    }
    __syncthreads();

    // MFMA proj: wave wq owns rows wq*16..+16; K=256 over 8 ks steps
    f32x4 acc[4];
    #pragma unroll
    for (int nt = 0; nt < 4; ++nt) acc[nt] = (f32x4)(0.f);
    const int arow = wq * 16 + (lane & 15);
    #pragma unroll
    for (int ks = 0; ks < 8; ++ks) {
        int c = ks * 4 + (lane >> 4);
        bf16x8 a = *(const bf16x8*)(smem + arow * 512 + (c ^ (arow & 7)) * 16);
        #pragma unroll
        for (int nt = 0; nt < 4; ++nt) {
            bf16x8 bb = *(const bf16x8*)(pwB + (((nt * 8 + ks) * 64 + lane) << 3));
            acc[nt] = __builtin_amdgcn_mfma_f32_16x16x32_bf16(a, bb, acc[nt], 0, 0, 0);
        }
    }
    __syncthreads();                                // all A-frag reads done

    // epilogue: bias, pooled_f (interp-adjoint gamma), restage output in LDS
    unsigned short* fosh = (unsigned short*)smem;   // 64 rows x 64 cols bf16 (8KB)
    float bias[4];
    #pragma unroll
    for (int nt = 0; nt < 4; ++nt) bias[nt] = pb[nt * 16 + (lane & 15)];
    float pf[4] = {0.f, 0.f, 0.f, 0.f};
    #pragma unroll
    for (int r = 0; r < 4; ++r) {
        int pl = wq * 16 + ((lane >> 4) << 2) + r;
        int p  = t0 + pl;
        float g = 0.f;
        if (p < TM1) {
            float mp  = mrow[p];
            float mp1 = mrow[p + 1];
            float wlo = (p + 1.5f) * (1.f / 2048.f);
            float whi = 1.f - (p + 0.5f) * (1.f / 2048.f);
            if (p == 0)          g = mp + mp1 * wlo;
            else if (p == 2046)  g = mp * whi + mp1;
            else                 g = mp * whi + mp1 * wlo;
        }
        #pragma unroll
        for (int nt = 0; nt < 4; ++nt) {
            float fv = acc[nt][r] + bias[nt];
            pf[nt] = fmaf(g, fv, pf[nt]);
            fosh[pl * 64 + nt * 16 + (lane & 15)] = (unsigned short)f2bf(fv);
        }
    }
    #pragma unroll
    for (int nt = 0; nt < 4; ++nt) {
        pf[nt] += __shfl_xor(pf[nt], 16);
        pf[nt] += __shfl_xor(pf[nt], 32);
    }
    if (lane < 16) {
        #pragma unroll
        for (int nt = 0; nt < 4; ++nt)
            atomicAdd(&pooled[bl * 64 + nt * 16 + lane], pf[nt]);
    }
    __syncthreads();

    // coalesced bf16 output: 512 chunks of 16B
    #pragma unroll
    for (int i = 0; i < 2; ++i) {
        int C = i * 256 + tid;
        int row = C >> 3, c = C & 7;
        int p = t0 + row;
        if (p < TM1) {
            uint4 vv = *(const uint4*)(smem + C * 16);
            *(uint4*)(fbf + ((size_t)bl * TM1 + p) * 64 + c * 8) = vv;
        }
    }
}

// ---------------- K2: SE gate (wave-parallel, per block) + apply + mask tail copy
// grid 2048 = 64 b x 32 t-segments of 64; 4 outputs/thread.
__global__ void k_apply2(const float* __restrict__ x, const unsigned short* __restrict__ fbf,
                         const float* __restrict__ pooled, const float* __restrict__ denom,
                         const float* __restrict__ mask,
                         const float* __restrict__ w1, const float* __restrict__ b1,
                         const float* __restrict__ w2, const float* __restrict__ b2,
                         float* __restrict__ out, float* __restrict__ out_mask)
{
    __shared__ __align__(16) float sgate[64];
    const int b  = blockIdx.x >> 5;
    const int t0 = (blockIdx.x & 31) << 6;
    const int tid = threadIdx.x;

    if (tid < 64) {
        // wave-parallel SE: lane l owns feature l
        float p = pooled[b * 64 + tid] / denom[b];
        float hp0 = p * w1[tid * 4 + 0];
        float hp1 = p * w1[tid * 4 + 1];
        float hp2 = p * w1[tid * 4 + 2];
        float hp3 = p * w1[tid * 4 + 3];
        #pragma unroll
        for (int off = 32; off >= 1; off >>= 1) {
            hp0 += __shfl_xor(hp0, off);
            hp1 += __shfl_xor(hp1, off);
            hp2 += __shfl_xor(hp2, off);
            hp3 += __shfl_xor(hp3, off);
        }
        float h0 = hp0 + b1[0], h1 = hp1 + b1[1], h2 = hp2 + b1[2], h3 = hp3 + b1[3];
        h0 = 0.5f * h0 * (1.f + erff(h0 * 0.70710678118654752f));
        h1 = 0.5f * h1 * (1.f + erff(h1 * 0.70710678118654752f));
        h2 = 0.5f * h2 * (1.f + erff(h2 * 0.70710678118654752f));
        h3 = 0.5f * h3 * (1.f + erff(h3 * 0.70710678118654752f));
        float sv = b2[tid];
        sv = fmaf(h0, w2[0 * 64 + tid], sv);
        sv = fmaf(h1, w2[1 * 64 + tid], sv);
        sv = fmaf(h2, w2[2 * 64 + tid], sv);
        sv = fmaf(h3, w2[3 * 64 + tid], sv);
        sgate[tid] = 1.f / (1.f + expf(-sv));
        // mask tail copy (out tuple element 1)
        out_mask[b * T_ + t0 + tid] = mask[b * T_ + t0 + tid];
    }
    __syncthreads();

    const unsigned short* fb = fbf + (size_t)b * (TM1 * 64);
    #pragma unroll
    for (int r = 0; r < 4; ++r) {
        int u  = r * 256 + tid;
        int t  = t0 + (u >> 4);
        int o4 = (u & 15) << 2;
        float pos = fminf(fmaxf((t + 0.5f) * (2047.f / 2048.f) - 0.5f, 0.f), 2046.f);
        int   i0  = (int)pos;
        float w   = pos - (float)i0;
        int   i1  = min(i0 + 1, 2046);
        uint2 u0 = *(const uint2*)(fb + i0 * 64 + o4);
        uint2 u1 = *(const uint2*)(fb + i1 * 64 + o4);
        size_t base = ((size_t)b * T_ + t) * 64 + o4;
        float4 xv = *(const float4*)(x + base);
        float4 sv = *(const float4*)(&sgate[o4]);
        float4 ov;
        float f00 = bf2f(u0.x & 0xffffu), f01 = bf2f(u0.x >> 16);
        float f02 = bf2f(u0.y & 0xffffu), f03 = bf2f(u0.y >> 16);
        float f10 = bf2f(u1.x & 0xffffu), f11 = bf2f(u1.x >> 16);
        float f12 = bf2f(u1.y & 0xffffu), f13 = bf2f(u1.y >> 16);
        ov.x = fmaf(xv.x + f00 * (1.f - w) + f10 * w, sv.x, xv.x);
        ov.y = fmaf(xv.y + f01 * (1.f - w) + f11 * w, sv.y, xv.y);
        ov.z = fmaf(xv.z + f02 * (1.f - w) + f12 * w, sv.z, xv.z);
        ov.w = fmaf(xv.w + f03 * (1.f - w) + f13 * w, sv.w, xv.w);
        *(float4*)(out + base) = ov;
    }
}

extern "C" void kernel_launch(void* const* d_in, const int* in_sizes, int n_in,
                              void* d_out, int out_size, void* d_ws, size_t ws_size,
                              hipStream_t stream)
{
    const float* x    = (const float*)d_in[0];
    const float* mask = (const float*)d_in[1];
    const float* Wd   = (const float*)d_in[2];
    const float* lng  = (const float*)d_in[3];
    const float* lnb  = (const float*)d_in[4];
    const float* pw   = (const float*)d_in[5];
    const float* pb   = (const float*)d_in[6];
    const float* sw1  = (const float*)d_in[7];
    const float* sb1  = (const float*)d_in[8];
    const float* sw2  = (const float*)d_in[9];
    const float* sb2  = (const float*)d_in[10];

    float* out      = (float*)d_out;
    float* out_mask = out + (size_t)B_ * T_ * D_;
    float* pooled = (float*)d_ws;                        // 4096
    float* denom  = pooled + 4096;                       // 64
    unsigned short* pwB = (unsigned short*)(denom + 64); // 16384 shorts (32KB)
    unsigned short* fbf = pwB + 16384;                   // B*TM1*64 shorts (16.8MB)

    hipLaunchKernelGGL(k_prep, dim3(64), dim3(256), 0, stream, pw, pwB, pooled);
    hipLaunchKernelGGL(k_expm_f3, dim3(2048), dim3(256), 0, stream,
                       x, mask, Wd, lng, lnb, pwB, pb, fbf, pooled, denom);
    hipLaunchKernelGGL(k_apply2, dim3(2048), dim3(256), 0, stream,
                       x, fbf, pooled, denom, mask, sw1, sb1, sw2, sb2, out, out_mask);
}

// Round 11
// 189.051 us; speedup vs baseline: 1.2712x; 1.0446x over previous
//
#include <hip/hip_runtime.h>

#define B_   64
#define T_   2048
#define TM1  2047
#define D_   64

#define PID(i,j) ((i)*((i)-1)/2 + (j))
#define UID(i,j) ((i)*8 + (j) - (i)*((i)+1)/2)   // upper-tri incl diag, i<=j

typedef __attribute__((ext_vector_type(8))) short bf16x8;
typedef __attribute__((ext_vector_type(4))) float f32x4;

__device__ __forceinline__ unsigned f2bf(float v) {
    unsigned u = __float_as_uint(v);
    u = (u + 0x7FFFu + ((u >> 16) & 1u)) >> 16;   // RNE
    return u;
}
__device__ __forceinline__ float bf2f(unsigned s) {
    return __uint_as_float(s << 16);
}

// ---------------- K0: pack proj_w B-fragments (bf16, 32KB) + zero pooled/denom
__global__ void k_prep(const float* __restrict__ pw, unsigned short* __restrict__ pwB,
                       float* __restrict__ pooled)
{
    int idx = blockIdx.x * 256 + threadIdx.x;     // 16384 total
    int j  = idx & 7;
    int l  = (idx >> 3) & 63;
    int ks = (idx >> 9) & 7;
    int nt = idx >> 12;
    int k  = ks * 32 + ((l >> 4) << 3) + j;
    int o  = nt * 16 + (l & 15);
    pwB[idx] = (unsigned short)f2bf(pw[k * 64 + o]);
    if (idx < 4160) pooled[idx] = 0.f;            // pooled[4096] + denom[64]
}

// ---------------- K1: x-pool + dX -> Mlie -> expm(s=4, deg-5 via (A+5I)c1 - (4I+B/3))
//                     -> LN -> MFMA proj -> f bf16 + pooled_f ; denom
// (256,3): AGPR-assisted budget ~170; peak live ~130 by construction (no c0 array,
// column-ordered c1 consumption). (256,4) hard-spills (R3: 1GB scratch traffic).
__global__ __launch_bounds__(256, 3) void k_expm_f4(
    const float* __restrict__ x, const float* __restrict__ mask,
    const float* __restrict__ Wd, const float* __restrict__ lng,
    const float* __restrict__ lnb, const unsigned short* __restrict__ pwB,
    const float* __restrict__ pb, unsigned short* __restrict__ fbf,
    float* __restrict__ pooled, float* __restrict__ denom)
{
    __shared__ __align__(16) unsigned char smem[32768];
    float* xT = (float*)smem;                       // phase 1: 64x65 f32 (16.6KB)

    const int tid  = threadIdx.x;
    const int lane = tid & 63;
    const int wq   = __builtin_amdgcn_readfirstlane(tid >> 6);
    const int bl   = blockIdx.x >> 5;
    const int t0   = (blockIdx.x & 31) << 6;

    const float* xb = x + (size_t)bl * (T_ * D_);
    for (int idx = tid; idx < 65 * 64; idx += 256) {
        int r = idx >> 6, c = idx & 63;
        int tr = t0 + r;
        xT[c * 65 + r] = (tr < T_) ? xb[tr * 64 + c] : 0.f;
    }
    __syncthreads();

    const int t = t0 + lane;
    const bool valid = (t < TM1);
    const float* mrow = mask + bl * T_;
    const float mk = valid ? mrow[t + 1] : 0.f;

    // fused masked x-pooling (xT live; rows t0..t0+63 belong to this block)
    {
        const int c  = tid & 63;
        const int rg = tid >> 6;
        float psum = 0.f;
        #pragma unroll
        for (int i = 0; i < 16; ++i) {
            int r = rg * 16 + i;
            psum = fmaf(xT[c * 65 + r], mrow[t0 + r], psum);
        }
        atomicAdd(&pooled[bl * 64 + c], psum);
        if (wq == 0) {
            float dv = mrow[t0 + lane];
            #pragma unroll
            for (int off = 32; off >= 1; off >>= 1) dv += __shfl_xor(dv, off);
            if (lane == 0) atomicAdd(&denom[bl], dv);
        }
    }

    float al[28];
    #pragma unroll
    for (int p = 0; p < 28; ++p) al[p] = 0.f;
    const float* Wg = Wd + wq * (16 * 64);
    #pragma unroll
    for (int d = 0; d < 16; ++d) {
        const float* col = &xT[(wq * 16 + d) * 65 + lane];
        float dxd = (col[1] - col[0]) * mk;
        const float* Wrow = Wg + d * 64;
        #pragma unroll
        for (int i = 1; i < 8; ++i)
            #pragma unroll
            for (int j = 0; j < i; ++j)
                al[PID(i, j)] = fmaf(dxd, Wrow[i * 8 + j], al[PID(i, j)]);
    }
    __syncthreads();                                // xT dead; smem reused for f staging

    #pragma unroll
    for (int p = 0; p < 28; ++p) al[p] *= 0.0625f;  // s=4 scaling

    // ---- B = A^2 (symmetric, ut36)
    float Bu[36];
    #pragma unroll
    for (int i = 0; i < 8; ++i)
        #pragma unroll
        for (int j = i; j < 8; ++j) {
            float s = 0.f;
            #pragma unroll
            for (int k = 0; k < 8; ++k) {
                if (k == i || k == j) continue;
                float aki = (k > i) ? al[PID(k, i)] : -al[PID(i, k)];
                float akj = (k > j) ? al[PID(k, j)] : -al[PID(j, k)];
                s = fmaf(aki, akj, s);
            }
            Bu[UID(i, j)] = -s;
        }
    // ---- c1 = I + B/6 + B^2/120 (B^2 element on the fly)
    float c1u[36];
    #pragma unroll
    for (int i = 0; i < 8; ++i)
        #pragma unroll
        for (int j = i; j < 8; ++j) {
            float s = 0.f;
            #pragma unroll
            for (int k = 0; k < 8; ++k) {
                int l1 = (i < k) ? i : k, h1 = (i < k) ? k : i;
                int l2 = (k < j) ? k : j, h2 = (k < j) ? j : k;
                s = fmaf(Bu[UID(l1, h1)], Bu[UID(l2, h2)], s);
            }
            float idm = (i == j) ? 1.f : 0.f;
            c1u[UID(i, j)] = fmaf(s, 1.f / 120.f, fmaf(Bu[UID(i, j)], 1.f / 6.f, idm));
        }
    // ---- E = 5*c1 - 4I - B/3, in place over Bu
    #pragma unroll
    for (int i = 0; i < 8; ++i)
        #pragma unroll
        for (int j = i; j < 8; ++j) {
            int id = UID(i, j);
            float idm = (i == j) ? 4.f : 0.f;
            Bu[id] = fmaf(c1u[id], 5.f, -idm) - Bu[id] * (1.f / 3.f);
        }
    // ---- R = E + A*c1  (column-ordered: c1/E entries die as R grows; peak ~130)
    float R[64];
    #pragma unroll
    for (int j = 0; j < 8; ++j)
        #pragma unroll
        for (int i = 0; i < 8; ++i) {
            int lo = (i < j) ? i : j, hi = (i < j) ? j : i;
            float s = Bu[UID(lo, hi)];
            #pragma unroll
            for (int k = 0; k < 8; ++k) {
                if (k == i) continue;
                float aik = (i > k) ? al[PID(i, k)] : -al[PID(k, i)];
                int l2 = (k < j) ? k : j, h2 = (k < j) ? j : k;
                s = fmaf(aik, c1u[UID(l2, h2)], s);
            }
            R[i * 8 + j] = s;
        }
    // ---- 4 squarings
    for (int sq = 0; sq < 4; ++sq) {
        float nw[64];
        #pragma unroll
        for (int i = 0; i < 8; ++i)
            #pragma unroll
            for (int j = 0; j < 8; ++j) {
                float s = 0.f;
                #pragma unroll
                for (int kk = 0; kk < 8; ++kk)
                    s = fmaf(R[i * 8 + kk], R[kk * 8 + j], s);
                nw[i * 8 + j] = s;
            }
        #pragma unroll
        for (int e = 0; e < 64; ++e) R[e] = nw[e];
    }

    float sum = 0.f, ssq = 0.f;
    #pragma unroll
    for (int e = 0; e < 64; ++e) { sum += R[e]; ssq = fmaf(R[e], R[e], ssq); }
    float mu   = sum * (1.f / 64.f);
    float var  = ssq * (1.f / 64.f) - mu * mu;
    float rstd = rsqrtf(var + 1e-5f);

    // stage LN'd f as bf16 into LDS: row=lane (512B), 8B slots XOR-swizzled
    #pragma unroll
    for (int eq = 0; eq < 16; ++eq) {
        int e = eq * 4;
        float v0 = fmaf((R[e]   - mu) * rstd, lng[e],   lnb[e]);
        float v1 = fmaf((R[e+1] - mu) * rstd, lng[e+1], lnb[e+1]);
        float v2 = fmaf((R[e+2] - mu) * rstd, lng[e+2], lnb[e+2]);
        float v3 = fmaf((R[e+3] - mu) * rstd, lng[e+3], lnb[e+3]);
        uint2 pk = make_uint2(f2bf(v0) | (f2bf(v1) << 16), f2bf(v2) | (f2bf(v3) << 16));
        int slot = wq * 16 + eq;
        int sw = slot ^ ((lane & 7) << 1);
        *(uint2*)(smem + lane * 512 + sw * 8) = pk;
    }
    __syncthreads();

    // MFMA proj: wave wq owns rows wq*16..+16; K=256 over 8 ks steps
    f32x4 acc[4];
    #pragma unroll
    for (int nt = 0; nt < 4; ++nt) acc[nt] = (f32x4)(0.f);
    const int arow = wq * 16 + (lane & 15);
    #pragma unroll
    for (int ks = 0; ks < 8; ++ks) {
        int c = ks * 4 + (lane >> 4);
        bf16x8 a = *(const bf16x8*)(smem + arow * 512 + (c ^ (arow & 7)) * 16);
        #pragma unroll
        for (int nt = 0; nt < 4; ++nt) {
            bf16x8 bb = *(const bf16x8*)(pwB + (((nt * 8 + ks) * 64 + lane) << 3));
            acc[nt] = __builtin_amdgcn_mfma_f32_16x16x32_bf16(a, bb, acc[nt], 0, 0, 0);
        }
    }
    __syncthreads();                                // all A-frag reads done

    // epilogue: bias, pooled_f (interp-adjoint gamma), restage output in LDS
    unsigned short* fosh = (unsigned short*)smem;   // 64 rows x 64 cols bf16 (8KB)
    float bias[4];
    #pragma unroll
    for (int nt = 0; nt < 4; ++nt) bias[nt] = pb[nt * 16 + (lane & 15)];
    float pf[4] = {0.f, 0.f, 0.f, 0.f};
    #pragma unroll
    for (int r = 0; r < 4; ++r) {
        int pl = wq * 16 + ((lane >> 4) << 2) + r;
        int p  = t0 + pl;
        float g = 0.f;
        if (p < TM1) {
            float mp  = mrow[p];
            float mp1 = mrow[p + 1];
            float wlo = (p + 1.5f) * (1.f / 2048.f);
            float whi = 1.f - (p + 0.5f) * (1.f / 2048.f);
            if (p == 0)          g = mp + mp1 * wlo;
            else if (p == 2046)  g = mp * whi + mp1;
            else                 g = mp * whi + mp1 * wlo;
        }
        #pragma unroll
        for (int nt = 0; nt < 4; ++nt) {
            float fv = acc[nt][r] + bias[nt];
            pf[nt] = fmaf(g, fv, pf[nt]);
            fosh[pl * 64 + nt * 16 + (lane & 15)] = (unsigned short)f2bf(fv);
        }
    }
    #pragma unroll
    for (int nt = 0; nt < 4; ++nt) {
        pf[nt] += __shfl_xor(pf[nt], 16);
        pf[nt] += __shfl_xor(pf[nt], 32);
    }
    if (lane < 16) {
        #pragma unroll
        for (int nt = 0; nt < 4; ++nt)
            atomicAdd(&pooled[bl * 64 + nt * 16 + lane], pf[nt]);
    }
    __syncthreads();

    // coalesced bf16 output: 512 chunks of 16B
    #pragma unroll
    for (int i = 0; i < 2; ++i) {
        int C = i * 256 + tid;
        int row = C >> 3, c = C & 7;
        int p = t0 + row;
        if (p < TM1) {
            uint4 vv = *(const uint4*)(smem + C * 16);
            *(uint4*)(fbf + ((size_t)bl * TM1 + p) * 64 + c * 8) = vv;
        }
    }
}

// ---------------- K2: SE gate (wave-parallel, per block) + apply + mask tail copy
// grid 4096 = 64 b x 64 t-segments of 32; 2x float4 per thread; NT loads/stores.
__global__ void k_apply2(const float* __restrict__ x, const unsigned short* __restrict__ fbf,
                         const float* __restrict__ pooled, const float* __restrict__ denom,
                         const float* __restrict__ mask,
                         const float* __restrict__ w1, const float* __restrict__ b1,
                         const float* __restrict__ w2, const float* __restrict__ b2,
                         float* __restrict__ out, float* __restrict__ out_mask)
{
    __shared__ __align__(16) float sgate[64];
    const int b  = blockIdx.x >> 6;
    const int t0 = (blockIdx.x & 63) << 5;
    const int tid = threadIdx.x;

    if (tid < 64) {
        float p = pooled[b * 64 + tid] / denom[b];
        float hp0 = p * w1[tid * 4 + 0];
        float hp1 = p * w1[tid * 4 + 1];
        float hp2 = p * w1[tid * 4 + 2];
        float hp3 = p * w1[tid * 4 + 3];
        #pragma unroll
        for (int off = 32; off >= 1; off >>= 1) {
            hp0 += __shfl_xor(hp0, off);
            hp1 += __shfl_xor(hp1, off);
            hp2 += __shfl_xor(hp2, off);
            hp3 += __shfl_xor(hp3, off);
        }
        float h0 = hp0 + b1[0], h1 = hp1 + b1[1], h2 = hp2 + b1[2], h3 = hp3 + b1[3];
        h0 = 0.5f * h0 * (1.f + erff(h0 * 0.70710678118654752f));
        h1 = 0.5f * h1 * (1.f + erff(h1 * 0.70710678118654752f));
        h2 = 0.5f * h2 * (1.f + erff(h2 * 0.70710678118654752f));
        h3 = 0.5f * h3 * (1.f + erff(h3 * 0.70710678118654752f));
        float sv = b2[tid];
        sv = fmaf(h0, w2[0 * 64 + tid], sv);
        sv = fmaf(h1, w2[1 * 64 + tid], sv);
        sv = fmaf(h2, w2[2 * 64 + tid], sv);
        sv = fmaf(h3, w2[3 * 64 + tid], sv);
        sgate[tid] = 1.f / (1.f + expf(-sv));
    }
    if (tid < 32) out_mask[b * T_ + t0 + tid] = mask[b * T_ + t0 + tid];
    __syncthreads();

    const unsigned short* fb = fbf + (size_t)b * (TM1 * 64);
    #pragma unroll
    for (int r = 0; r < 2; ++r) {
        int u  = r * 256 + tid;
        int t  = t0 + (u >> 4);
        int o4 = (u & 15) << 2;
        float pos = fminf(fmaxf((t + 0.5f) * (2047.f / 2048.f) - 0.5f, 0.f), 2046.f);
        int   i0  = (int)pos;
        float w   = pos - (float)i0;
        int   i1  = min(i0 + 1, 2046);
        uint2 u0 = *(const uint2*)(fb + i0 * 64 + o4);
        uint2 u1 = *(const uint2*)(fb + i1 * 64 + o4);
        size_t base = ((size_t)b * T_ + t) * 64 + o4;
        f32x4 xv = __builtin_nontemporal_load((const f32x4*)(x + base));
        f32x4 sv = *(const f32x4*)(&sgate[o4]);
        f32x4 ov;
        float f00 = bf2f(u0.x & 0xffffu), f01 = bf2f(u0.x >> 16);
        float f02 = bf2f(u0.y & 0xffffu), f03 = bf2f(u0.y >> 16);
        float f10 = bf2f(u1.x & 0xffffu), f11 = bf2f(u1.x >> 16);
        float f12 = bf2f(u1.y & 0xffffu), f13 = bf2f(u1.y >> 16);
        ov.x = fmaf(xv.x + f00 * (1.f - w) + f10 * w, sv.x, xv.x);
        ov.y = fmaf(xv.y + f01 * (1.f - w) + f11 * w, sv.y, xv.y);
        ov.z = fmaf(xv.z + f02 * (1.f - w) + f12 * w, sv.z, xv.z);
        ov.w = fmaf(xv.w + f03 * (1.f - w) + f13 * w, sv.w, xv.w);
        __builtin_nontemporal_store(ov, (f32x4*)(out + base));
    }
}

extern "C" void kernel_launch(void* const* d_in, const int* in_sizes, int n_in,
                              void* d_out, int out_size, void* d_ws, size_t ws_size,
                              hipStream_t stream)
{
    const float* x    = (const float*)d_in[0];
    const float* mask = (const float*)d_in[1];
    const float* Wd   = (const float*)d_in[2];
    const float* lng  = (const float*)d_in[3];
    const float* lnb  = (const float*)d_in[4];
    const float* pw   = (const float*)d_in[5];
    const float* pb   = (const float*)d_in[6];
    const float* sw1  = (const float*)d_in[7];
    const float* sb1  = (const float*)d_in[8];
    const float* sw2  = (const float*)d_in[9];
    const float* sb2  = (const float*)d_in[10];

    float* out      = (float*)d_out;
    float* out_mask = out + (size_t)B_ * T_ * D_;
    float* pooled = (float*)d_ws;                        // 4096
    float* denom  = pooled + 4096;                       // 64
    unsigned short* pwB = (unsigned short*)(denom + 64); // 16384 shorts (32KB)
    unsigned short* fbf = pwB + 16384;                   // B*TM1*64 shorts (16.8MB)

    hipLaunchKernelGGL(k_prep, dim3(64), dim3(256), 0, stream, pw, pwB, pooled);
    hipLaunchKernelGGL(k_expm_f4, dim3(2048), dim3(256), 0, stream,
                       x, mask, Wd, lng, lnb, pwB, pb, fbf, pooled, denom);
    hipLaunchKernelGGL(k_apply2, dim3(4096), dim3(256), 0, stream,
                       x, fbf, pooled, denom, mask, sw1, sb1, sw2, sb2, out, out_mask);
}